// Round 14
// baseline (459.910 us; speedup 1.0000x reference)
//
#include <hip/hip_runtime.h>

#define TSTEPS 512   // LSTM sequence length (2048/4)
#define HID    64

typedef _Float16 f16x2 __attribute__((ext_vector_type(2)));

#if __has_builtin(__builtin_amdgcn_exp2f)
#define EXP2F(x) __builtin_amdgcn_exp2f(x)
#else
#define EXP2F(x) exp2f(x)
#endif
#if __has_builtin(__builtin_amdgcn_rcpf)
#define RCPF(x) __builtin_amdgcn_rcpf(x)
#else
#define RCPF(x) (1.0f / (x))
#endif

#define CL   1.4426950408889634f   // log2(e)
#define C2L  2.8853900817779268f   // 2*log2(e)
#define C4L  5.7707801635558536f   // 4*log2(e)

// quad-lane butterfly add via DPP quad_perm (VALU-only, no LDS pipe)
#define DPP_ADD(x, ctrl)                                                       \
  x += __int_as_float(                                                         \
      __builtin_amdgcn_mov_dpp(__float_as_int(x), (ctrl), 0xf, 0xf, true))

// v_dot2_f32_f16: acc += a.x*b.x + a.y*b.y  (2 MACs/instr, f32 accumulate)
#if __has_builtin(__builtin_amdgcn_fdot2)
#define FDOT2(acc, a, b) acc = __builtin_amdgcn_fdot2((a), (b), (acc), false)
#else
#define FDOT2(acc, a, b)                                                       \
  acc = fmaf((float)(a).x, (float)(b).x,                                       \
             fmaf((float)(a).y, (float)(b).y, (acc)))
#endif

__device__ __forceinline__ f16x2 pk2(float a, float b, float sc) {
  return (f16x2){(_Float16)(a * sc), (_Float16)(b * sc)};
}

__device__ __forceinline__ void ldh4(const void* p, f16x2& a, f16x2& b,
                                     f16x2& c, f16x2& d) {
  const uint4 t = *(const uint4*)p;
  a = __builtin_bit_cast(f16x2, t.x);
  b = __builtin_bit_cast(f16x2, t.y);
  c = __builtin_bit_cast(f16x2, t.z);
  d = __builtin_bit_cast(f16x2, t.w);
}

// spin until min(c[0..3]) >= need (LDS seq counters). Capped: cannot hang.
__device__ __forceinline__ void wait_ge(volatile unsigned int* c, int need) {
  if (need <= 0) return;
  for (int spin = 0; spin < 4096; ++spin) {
    const unsigned m0 = c[0], m1 = c[1], m2 = c[2], m3 = c[3];
    unsigned m = m0 < m1 ? m0 : m1;
    const unsigned n = m2 < m3 ? m2 : m3;
    m = m < n ? m : n;
    if ((int)m >= need) break;
  }
  asm volatile("" ::: "memory");          // IR-level fence for later LDS reads
  __builtin_amdgcn_sched_barrier(0);      // backend fence (rule #18)
}

// ---------------------------------------------------------------------------
// ONE kernel: conv1+pool -> t1 (global, L2-resident), conv2+pool -> featB
// (LDS, f16), 2-layer pipelined LSTM recurrence + fc.
// One block per batch element: 256 blocks x 512 threads (1 block/CU).
//
// v14 = v13 (f16 fdot2 core, exp2-domain tail) with the per-step
// __syncthreads REPLACED by LDS sequence-counter producer/consumer sync:
//   - each wave publishes "completed iter t" (counter = t+1) after
//     s_waitcnt lgkmcnt(0); consumers spin on min(group counters).
//   - h0/h1 are 4-deep rings -> 3 steps of slack decouples the L0 group
//     from the L1 group (no block-wide rendezvous each step; the measured
//     1522cy/iter interval vs ~500cy of chain+issue was barrier lockstep).
//   - wait conditions (deadlock-checked): L0@t: c0min>=t && c1min>=t-2;
//     L1@t: c0min>=t && c1min>=t. All waves tick counters every iter.
//   - L0's x-dots run BEFORE its wait (featB static) to shorten the
//     post-wait chain. Spin is capped (no hang possible).
// ---------------------------------------------------------------------------
__global__ __launch_bounds__(512, 1) void fused_all(
    const float* __restrict__ x,
    const float* __restrict__ c1w, const float* __restrict__ c1b,
    const float* __restrict__ c2w, const float* __restrict__ c2b,
    const float* __restrict__ w_ih0, const float* __restrict__ w_hh0,
    const float* __restrict__ b_ih0, const float* __restrict__ b_hh0,
    const float* __restrict__ w_ih1, const float* __restrict__ w_hh1,
    const float* __restrict__ b_ih1, const float* __restrict__ b_hh1,
    const float* __restrict__ fc_w, const float* __restrict__ fc_b,
    float* __restrict__ t1g, float* __restrict__ out) {
  __shared__ __align__(16) _Float16 featB[512 * 32];   // 32 KB, f16
  __shared__ float ws1[144];                           // conv1 w [16][3][3]
  __shared__ float bs1[16];
  __shared__ float ws2[1536];                          // conv2 w [32][16][3]
  __shared__ float bs2[32];
  __shared__ __align__(16) _Float16 h0r[4][64];        // h0 ring (4 deep), f16
  __shared__ __align__(16) _Float16 h1r[4][64];        // h1 ring (4 deep), f16
  __shared__ __align__(16) unsigned int c0s[4];        // L0 wave seq counters
  __shared__ __align__(16) unsigned int c1s[4];        // L1 wave seq counters

  const int tid = threadIdx.x;
  const int b = blockIdx.x;

  // ---- conv weights to LDS + sync state init ----
  if (tid < 144) ws1[tid] = c1w[tid];
  if (tid < 16)  bs1[tid] = c1b[tid];
  for (int i = tid; i < 1536; i += 512) ws2[i] = c2w[i];
  if (tid < 32)  bs2[tid] = c2b[tid];
  if (tid < 4) { c0s[tid] = 0; c1s[tid] = 0; }
  if (tid < 256) {
    ((_Float16*)h0r)[tid] = (_Float16)0.f;
    ((_Float16*)h1r)[tid] = (_Float16)0.f;
  }
  __syncthreads();

  // ---- phase 1: conv1 (3->16, k=3, same) + maxpool2, 2 positions/thread ----
  const float* xb = x + (size_t)b * 2048 * 3;
  float* t1b = t1g + (size_t)b * 1024 * 16;
#pragma unroll
  for (int rep = 0; rep < 2; ++rep) {
    const int t2 = rep * 512 + tid;       // pooled position 0..1023
    const int p0 = 2 * t2;
    float xv[4][3];
#pragma unroll
    for (int j = 0; j < 4; ++j) {
      const int p = p0 - 1 + j;
      const bool ok = (p >= 0) && (p < 2048);
#pragma unroll
      for (int c = 0; c < 3; ++c) xv[j][c] = ok ? xb[p * 3 + c] : 0.0f;
    }
    float4 o4[4];
    float* op = (float*)o4;
#pragma unroll
    for (int o = 0; o < 16; ++o) {
      float s0 = bs1[o], s1 = bs1[o];
#pragma unroll
      for (int c = 0; c < 3; ++c) {
#pragma unroll
        for (int k = 0; k < 3; ++k) {
          const float wv = ws1[(o * 3 + c) * 3 + k];
          s0 = fmaf(xv[k][c],     wv, s0);
          s1 = fmaf(xv[k + 1][c], wv, s1);
        }
      }
      op[o] = fmaxf(s0, s1);
    }
    float4* dst = (float4*)(t1b + (size_t)t2 * 16);
    dst[0] = o4[0]; dst[1] = o4[1]; dst[2] = o4[2]; dst[3] = o4[3];
  }
  __syncthreads();   // t1 writes visible block-wide

  // ---- phase 2: conv2 (16->32, k=3, same) + maxpool2 -> featB (f16) ----
  {
    const int t2 = tid;                   // pooled position 0..511
    const int p0 = 2 * t2;
    float4 r4[4][4];
    float* r = (float*)r4;                // r[j*16 + c]
#pragma unroll
    for (int j = 0; j < 4; ++j) {
      const int p = p0 - 1 + j;
      if (p >= 0 && p < 1024) {
        const float4* s = (const float4*)(t1b + p * 16);
        r4[j][0] = s[0]; r4[j][1] = s[1]; r4[j][2] = s[2]; r4[j][3] = s[3];
      } else {
        const float4 z = {0.f, 0.f, 0.f, 0.f};
        r4[j][0] = z; r4[j][1] = z; r4[j][2] = z; r4[j][3] = z;
      }
    }
    _Float16* dst = featB + (size_t)t2 * 32;
#pragma unroll 4
    for (int o = 0; o < 32; ++o) {
      float s0 = bs2[o], s1 = bs2[o];
      const float* wo = &ws2[o * 48];
#pragma unroll
      for (int c = 0; c < 16; ++c) {
        const float w0 = wo[c * 3], w1 = wo[c * 3 + 1], w2 = wo[c * 3 + 2];
        s0 = fmaf(r[0 * 16 + c], w0, s0);
        s0 = fmaf(r[1 * 16 + c], w1, s0);
        s0 = fmaf(r[2 * 16 + c], w2, s0);
        s1 = fmaf(r[1 * 16 + c], w0, s1);
        s1 = fmaf(r[2 * 16 + c], w1, s1);
        s1 = fmaf(r[3 * 16 + c], w2, s1);
      }
      dst[o] = (_Float16)fmaxf(s0, s1);
    }
  }

  // ---- phase 3: LSTM weight load -> f16 pairs, pre-scaled by log2e ----
  const int layer = tid >> 8;   // 0 or 1 (wave-uniform)
  const int wv = tid >> 6;      // wave 0..7 (L0: 0-3, L1: 4-7)
  const int lt  = tid & 255;
  const int u = lt >> 2;        // unit 0..63
  const int q = lt & 3;         // dim-quarter / quad slot

  f16x2 wx[32], wh[32];
  float bi[4];
  if (layer == 0) {
#pragma unroll
    for (int j = 0; j < 4; ++j) {
      const int rrow = j * 64 + u;
      const float sc = (j == 2) ? C2L : CL;
      const float4* px = (const float4*)(w_ih0 + (size_t)rrow * 32 + q * 8);
      const float4 p0 = px[0], p1 = px[1];
      wx[j * 4 + 0] = pk2(p0.x, p0.y, sc);
      wx[j * 4 + 1] = pk2(p0.z, p0.w, sc);
      wx[j * 4 + 2] = pk2(p1.x, p1.y, sc);
      wx[j * 4 + 3] = pk2(p1.z, p1.w, sc);
      const float4* ph = (const float4*)(w_hh0 + (size_t)rrow * 64 + q * 16);
#pragma unroll
      for (int k = 0; k < 4; ++k) {
        const float4 tw = ph[k];
        wh[j * 8 + 2 * k]     = pk2(tw.x, tw.y, sc);
        wh[j * 8 + 2 * k + 1] = pk2(tw.z, tw.w, sc);
      }
      const float bsc = (b_ih0[rrow] + b_hh0[rrow]) * sc;
      bi[j] = (q == 0) ? bsc : 0.0f;
    }
  } else {
#pragma unroll
    for (int j = 0; j < 4; ++j) {
      const int rrow = j * 64 + u;
      const float sc = (j == 2) ? C2L : CL;
      const float4* px = (const float4*)(w_ih1 + (size_t)rrow * 64 + q * 16);
#pragma unroll
      for (int k = 0; k < 4; ++k) {
        const float4 tw = px[k];
        wx[j * 8 + 2 * k]     = pk2(tw.x, tw.y, sc);
        wx[j * 8 + 2 * k + 1] = pk2(tw.z, tw.w, sc);
      }
      const float4* ph = (const float4*)(w_hh1 + (size_t)rrow * 64 + q * 16);
#pragma unroll
      for (int k = 0; k < 4; ++k) {
        const float4 tw = ph[k];
        wh[j * 8 + 2 * k]     = pk2(tw.x, tw.y, sc);
        wh[j * 8 + 2 * k + 1] = pk2(tw.z, tw.w, sc);
      }
      const float bsc = (b_ih1[rrow] + b_hh1[rrow]) * sc;
      bi[j] = (q == 0) ? bsc : 0.0f;
    }
  }

  // featB + rings + counters must be visible to all waves before the loop
  __syncthreads();

  float cc = 0.0f;   // cell state SCALED by 2*log2e, redundant in quad

  // ---- phase 4: recurrence, 513 iters, NO block barrier ----
  for (int t = 0; t <= TSTEPS; ++t) {
    if (layer == 0) {
      if (t < TSTEPS) {
        float a0 = bi[0], a1 = bi[1], a2 = bi[2], a3 = bi[3];
        // x-part first: featB is static, no sync needed (hides spin latency)
        f16x2 xa0, xa1, xa2, xa3;
        ldh4(featB + t * 32 + q * 8, xa0, xa1, xa2, xa3);
        FDOT2(a0, wx[0],  xa0); FDOT2(a0, wx[1],  xa1);
        FDOT2(a0, wx[2],  xa2); FDOT2(a0, wx[3],  xa3);
        FDOT2(a1, wx[4],  xa0); FDOT2(a1, wx[5],  xa1);
        FDOT2(a1, wx[6],  xa2); FDOT2(a1, wx[7],  xa3);
        FDOT2(a2, wx[8],  xa0); FDOT2(a2, wx[9],  xa1);
        FDOT2(a2, wx[10], xa2); FDOT2(a2, wx[11], xa3);
        FDOT2(a3, wx[12], xa0); FDOT2(a3, wx[13], xa1);
        FDOT2(a3, wx[14], xa2); FDOT2(a3, wx[15], xa3);
        // wait: h0[t-1] ready; L1 done reading h0[t-4] (ring safety)
        wait_ge(c0s, t);
        wait_ge(c1s, t - 2);
        // h-part: h0[t-1] from ring slot (t-1)&3
        const _Float16* hp = h0r[(t - 1) & 3] + q * 16;
        f16x2 hv[8];
        ldh4(hp,     hv[0], hv[1], hv[2], hv[3]);
        ldh4(hp + 8, hv[4], hv[5], hv[6], hv[7]);
#pragma unroll
        for (int dd = 0; dd < 8; ++dd) {
          FDOT2(a0, wh[dd],      hv[dd]);
          FDOT2(a1, wh[8 + dd],  hv[dd]);
          FDOT2(a2, wh[16 + dd], hv[dd]);
          FDOT2(a3, wh[24 + dd], hv[dd]);
        }
        DPP_ADD(a0, 0xB1); DPP_ADD(a1, 0xB1); DPP_ADD(a2, 0xB1); DPP_ADD(a3, 0xB1);
        DPP_ADD(a0, 0x4E); DPP_ADD(a1, 0x4E); DPP_ADD(a2, 0x4E); DPP_ADD(a3, 0x4E);
        const float ii = RCPF(1.0f + EXP2F(-a0));
        const float ff = RCPF(1.0f + EXP2F(-a1));
        const float gs = fmaf(-C4L, RCPF(1.0f + EXP2F(a2)), C2L);
        const float oo = RCPF(1.0f + EXP2F(-a3));
        cc = fmaf(ff, cc, ii * gs);
        const float th = fmaf(-2.0f, RCPF(1.0f + EXP2F(cc)), 1.0f);
        if (q == 0) h0r[t & 3][u] = (_Float16)(oo * th);   // h0[t]
      }
      // publish completion of iter t (h0[t] visible first)
      asm volatile("s_waitcnt lgkmcnt(0)" ::: "memory");
      if ((tid & 63) == 0) c0s[wv] = (unsigned)(t + 1);
    } else {
      if (t >= 1) {
        // wait: h0[t-1] ready; own group done iter t-1 (h1[t-2] ready)
        wait_ge(c0s, t);
        wait_ge(c1s, t);
        float a0 = bi[0], a1 = bi[1], a2 = bi[2], a3 = bi[3];
        const _Float16* xp = h0r[(t - 1) & 3] + q * 16;
        f16x2 xv[8];
        ldh4(xp,     xv[0], xv[1], xv[2], xv[3]);
        ldh4(xp + 8, xv[4], xv[5], xv[6], xv[7]);
        const _Float16* hp = h1r[(t - 2) & 3] + q * 16;
        f16x2 hv[8];
        ldh4(hp,     hv[0], hv[1], hv[2], hv[3]);
        ldh4(hp + 8, hv[4], hv[5], hv[6], hv[7]);
#pragma unroll
        for (int dd = 0; dd < 8; ++dd) {
          FDOT2(a0, wx[dd],      xv[dd]);
          FDOT2(a1, wx[8 + dd],  xv[dd]);
          FDOT2(a2, wx[16 + dd], xv[dd]);
          FDOT2(a3, wx[24 + dd], xv[dd]);
        }
#pragma unroll
        for (int dd = 0; dd < 8; ++dd) {
          FDOT2(a0, wh[dd],      hv[dd]);
          FDOT2(a1, wh[8 + dd],  hv[dd]);
          FDOT2(a2, wh[16 + dd], hv[dd]);
          FDOT2(a3, wh[24 + dd], hv[dd]);
        }
        DPP_ADD(a0, 0xB1); DPP_ADD(a1, 0xB1); DPP_ADD(a2, 0xB1); DPP_ADD(a3, 0xB1);
        DPP_ADD(a0, 0x4E); DPP_ADD(a1, 0x4E); DPP_ADD(a2, 0x4E); DPP_ADD(a3, 0x4E);
        const float ii = RCPF(1.0f + EXP2F(-a0));
        const float ff = RCPF(1.0f + EXP2F(-a1));
        const float gs = fmaf(-C4L, RCPF(1.0f + EXP2F(a2)), C2L);
        const float oo = RCPF(1.0f + EXP2F(-a3));
        cc = fmaf(ff, cc, ii * gs);
        const float th = fmaf(-2.0f, RCPF(1.0f + EXP2F(cc)), 1.0f);
        if (q == 0) h1r[(t - 1) & 3][u] = (_Float16)(oo * th);  // h1[t-1]
      }
      // publish completion of iter t (h1[t-1] visible first)
      asm volatile("s_waitcnt lgkmcnt(0)" ::: "memory");
      if ((tid & 63) == 0) c1s[wv & 3] = (unsigned)(t + 1);
    }
  }
  __syncthreads();

  // fc epilogue: h1[T-1] lives in ring slot (T-1)&3
  if (tid < 5) {
    const _Float16* h = h1r[(TSTEPS - 1) & 3];
    float s = fc_b[tid];
    const float* wrow = fc_w + tid * HID;
#pragma unroll
    for (int j = 0; j < HID; ++j) s = fmaf(wrow[j], (float)h[j], s);
    out[b * 5 + tid] = s;
  }
}

// ---------------------------------------------------------------------------
extern "C" void kernel_launch(void* const* d_in, const int* in_sizes, int n_in,
                              void* d_out, int out_size, void* d_ws, size_t ws_size,
                              hipStream_t stream) {
  (void)in_sizes; (void)n_in; (void)out_size; (void)ws_size;
  const float* x    = (const float*)d_in[0];
  const float* c1w  = (const float*)d_in[1];
  const float* c1b  = (const float*)d_in[2];
  const float* c2w  = (const float*)d_in[3];
  const float* c2b  = (const float*)d_in[4];
  const float* wih0 = (const float*)d_in[5];
  const float* whh0 = (const float*)d_in[6];
  const float* bih0 = (const float*)d_in[7];
  const float* bhh0 = (const float*)d_in[8];
  const float* wih1 = (const float*)d_in[9];
  const float* whh1 = (const float*)d_in[10];
  const float* bih1 = (const float*)d_in[11];
  const float* bhh1 = (const float*)d_in[12];
  const float* fcw  = (const float*)d_in[13];
  const float* fcb  = (const float*)d_in[14];
  float* out = (float*)d_out;

  float* t1 = (float*)d_ws;    // [256,1024,16] = 16 MB (L2-resident per block)

  fused_all<<<256, 512, 0, stream>>>(x, c1w, c1b, c2w, c2b,
                                     wih0, whh0, bih0, bhh0,
                                     wih1, whh1, bih1, bhh1,
                                     fcw, fcb, t1, out);
}

// Round 15
// 387.806 us; speedup vs baseline: 1.1859x; 1.1859x over previous
//
#include <hip/hip_runtime.h>

#define TSTEPS 512   // LSTM sequence length (2048/4)
#define HID    64

typedef _Float16 f16x2 __attribute__((ext_vector_type(2)));

#if __has_builtin(__builtin_amdgcn_exp2f)
#define EXP2F(x) __builtin_amdgcn_exp2f(x)
#else
#define EXP2F(x) exp2f(x)
#endif
#if __has_builtin(__builtin_amdgcn_rcpf)
#define RCPF(x) __builtin_amdgcn_rcpf(x)
#else
#define RCPF(x) (1.0f / (x))
#endif

#define CL   1.4426950408889634f   // log2(e)
#define C2L  2.8853900817779268f   // 2*log2(e)
#define C4L  5.7707801635558536f   // 4*log2(e)

// quad-lane DPP add / move (VALU-only, no LDS pipe)
#define DPP_ADD(x, ctrl)                                                       \
  x += __int_as_float(                                                         \
      __builtin_amdgcn_mov_dpp(__float_as_int(x), (ctrl), 0xf, 0xf, true))
#define DPP_MOV(d, x, ctrl)                                                    \
  d = __int_as_float(                                                          \
      __builtin_amdgcn_mov_dpp(__float_as_int(x), (ctrl), 0xf, 0xf, true))

// v_dot2_f32_f16: acc += a.x*b.x + a.y*b.y  (2 MACs/instr, f32 accumulate)
#if __has_builtin(__builtin_amdgcn_fdot2)
#define FDOT2(acc, a, b) acc = __builtin_amdgcn_fdot2((a), (b), (acc), false)
#else
#define FDOT2(acc, a, b)                                                       \
  acc = fmaf((float)(a).x, (float)(b).x,                                       \
             fmaf((float)(a).y, (float)(b).y, (acc)))
#endif

__device__ __forceinline__ f16x2 pk2(float a, float b, float sc) {
  return (f16x2){(_Float16)(a * sc), (_Float16)(b * sc)};
}

__device__ __forceinline__ void ldh4(const void* p, f16x2& a, f16x2& b,
                                     f16x2& c, f16x2& d) {
  const uint4 t = *(const uint4*)p;
  a = __builtin_bit_cast(f16x2, t.x);
  b = __builtin_bit_cast(f16x2, t.y);
  c = __builtin_bit_cast(f16x2, t.z);
  d = __builtin_bit_cast(f16x2, t.w);
}

// ---------------------------------------------------------------------------
// ONE kernel: conv1+pool -> t1 (global, L2-resident), conv2+pool -> featB
// (LDS, f16), 2-layer pipelined LSTM recurrence + fc.
// One block per batch element: 256 blocks x 512 threads (1 block/CU).
//
// v15 = v13 (f16 fdot2 core, barrier/step — v14's spin-sync regressed) with
// LANE-PARALLEL ACTIVATIONS: after the quad all-reduce every lane holds all
// 4 gate sums; lane q activates only gate q via one uniform form
// k1 + k2*rcp(1+exp2(aq)) (weights pre-SIGNED at load: i,f,o by -log2e,
// g by +2log2e), then a 3-mov_dpp quad gather lands (ii,ff,gs,oo) in lane 0.
// TRANS ops per wave per iter: 10 -> 4 (quarter-rate pipe was the last
// identified tail consumer; R11 showed tail instrs cost ~12cy each).
// Lanes q!=0 compute garbage cc/h — harmless: only q==0 writes, and cc
// never feeds the dot-products.
// ---------------------------------------------------------------------------
__global__ __launch_bounds__(512, 1) void fused_all(
    const float* __restrict__ x,
    const float* __restrict__ c1w, const float* __restrict__ c1b,
    const float* __restrict__ c2w, const float* __restrict__ c2b,
    const float* __restrict__ w_ih0, const float* __restrict__ w_hh0,
    const float* __restrict__ b_ih0, const float* __restrict__ b_hh0,
    const float* __restrict__ w_ih1, const float* __restrict__ w_hh1,
    const float* __restrict__ b_ih1, const float* __restrict__ b_hh1,
    const float* __restrict__ fc_w, const float* __restrict__ fc_b,
    float* __restrict__ t1g, float* __restrict__ out) {
  __shared__ __align__(16) _Float16 featB[512 * 32];   // 32 KB, f16
  __shared__ float ws1[144];                           // conv1 w [16][3][3]
  __shared__ float bs1[16];
  __shared__ float ws2[1536];                          // conv2 w [32][16][3]
  __shared__ float bs2[32];
  __shared__ __align__(16) _Float16 h0s[2][64];        // h0 double buffer, f16
  __shared__ __align__(16) _Float16 h1s[2][64];        // h1 double buffer, f16

  const int tid = threadIdx.x;
  const int b = blockIdx.x;

  // ---- conv weights to LDS ----
  if (tid < 144) ws1[tid] = c1w[tid];
  if (tid < 16)  bs1[tid] = c1b[tid];
  for (int i = tid; i < 1536; i += 512) ws2[i] = c2w[i];
  if (tid < 32)  bs2[tid] = c2b[tid];
  __syncthreads();

  // ---- phase 1: conv1 (3->16, k=3, same) + maxpool2, 2 positions/thread ----
  const float* xb = x + (size_t)b * 2048 * 3;
  float* t1b = t1g + (size_t)b * 1024 * 16;
#pragma unroll
  for (int rep = 0; rep < 2; ++rep) {
    const int t2 = rep * 512 + tid;       // pooled position 0..1023
    const int p0 = 2 * t2;
    float xv[4][3];
#pragma unroll
    for (int j = 0; j < 4; ++j) {
      const int p = p0 - 1 + j;
      const bool ok = (p >= 0) && (p < 2048);
#pragma unroll
      for (int c = 0; c < 3; ++c) xv[j][c] = ok ? xb[p * 3 + c] : 0.0f;
    }
    float4 o4[4];
    float* op = (float*)o4;
#pragma unroll
    for (int o = 0; o < 16; ++o) {
      float s0 = bs1[o], s1 = bs1[o];
#pragma unroll
      for (int c = 0; c < 3; ++c) {
#pragma unroll
        for (int k = 0; k < 3; ++k) {
          const float wv = ws1[(o * 3 + c) * 3 + k];
          s0 = fmaf(xv[k][c],     wv, s0);
          s1 = fmaf(xv[k + 1][c], wv, s1);
        }
      }
      op[o] = fmaxf(s0, s1);
    }
    float4* dst = (float4*)(t1b + (size_t)t2 * 16);
    dst[0] = o4[0]; dst[1] = o4[1]; dst[2] = o4[2]; dst[3] = o4[3];
  }
  __syncthreads();   // t1 writes visible block-wide

  // ---- phase 2: conv2 (16->32, k=3, same) + maxpool2 -> featB (f16) ----
  {
    const int t2 = tid;                   // pooled position 0..511
    const int p0 = 2 * t2;
    float4 r4[4][4];
    float* r = (float*)r4;                // r[j*16 + c]
#pragma unroll
    for (int j = 0; j < 4; ++j) {
      const int p = p0 - 1 + j;
      if (p >= 0 && p < 1024) {
        const float4* s = (const float4*)(t1b + p * 16);
        r4[j][0] = s[0]; r4[j][1] = s[1]; r4[j][2] = s[2]; r4[j][3] = s[3];
      } else {
        const float4 z = {0.f, 0.f, 0.f, 0.f};
        r4[j][0] = z; r4[j][1] = z; r4[j][2] = z; r4[j][3] = z;
      }
    }
    _Float16* dst = featB + (size_t)t2 * 32;
#pragma unroll 4
    for (int o = 0; o < 32; ++o) {
      float s0 = bs2[o], s1 = bs2[o];
      const float* wo = &ws2[o * 48];
#pragma unroll
      for (int c = 0; c < 16; ++c) {
        const float w0 = wo[c * 3], w1 = wo[c * 3 + 1], w2 = wo[c * 3 + 2];
        s0 = fmaf(r[0 * 16 + c], w0, s0);
        s0 = fmaf(r[1 * 16 + c], w1, s0);
        s0 = fmaf(r[2 * 16 + c], w2, s0);
        s1 = fmaf(r[1 * 16 + c], w0, s1);
        s1 = fmaf(r[2 * 16 + c], w1, s1);
        s1 = fmaf(r[3 * 16 + c], w2, s1);
      }
      dst[o] = (_Float16)fmaxf(s0, s1);
    }
  }

  // ---- phase 3: LSTM weight load -> f16 pairs, pre-SIGNED+scaled ----
  const int layer = tid >> 8;   // 0 or 1 (wave-uniform)
  const int lt  = tid & 255;
  const int u = lt >> 2;        // unit 0..63
  const int q = lt & 3;         // dim-quarter / quad slot

  // gate j sign+scale: i,f,o -> -log2e (so act = rcp(1+exp2(a)) = sigmoid);
  // g -> +2log2e (so C2L - C4L*rcp(1+exp2(a)) = 2L*tanh)
  f16x2 wx[32], wh[32];
  float bi[4];
  if (layer == 0) {
#pragma unroll
    for (int j = 0; j < 4; ++j) {
      const int rrow = j * 64 + u;
      const float sc = (j == 2) ? C2L : -CL;
      const float4* px = (const float4*)(w_ih0 + (size_t)rrow * 32 + q * 8);
      const float4 p0 = px[0], p1 = px[1];
      wx[j * 4 + 0] = pk2(p0.x, p0.y, sc);
      wx[j * 4 + 1] = pk2(p0.z, p0.w, sc);
      wx[j * 4 + 2] = pk2(p1.x, p1.y, sc);
      wx[j * 4 + 3] = pk2(p1.z, p1.w, sc);
      const float4* ph = (const float4*)(w_hh0 + (size_t)rrow * 64 + q * 16);
#pragma unroll
      for (int k = 0; k < 4; ++k) {
        const float4 tw = ph[k];
        wh[j * 8 + 2 * k]     = pk2(tw.x, tw.y, sc);
        wh[j * 8 + 2 * k + 1] = pk2(tw.z, tw.w, sc);
      }
      const float bsc = (b_ih0[rrow] + b_hh0[rrow]) * sc;
      bi[j] = (q == 0) ? bsc : 0.0f;
    }
  } else {
#pragma unroll
    for (int j = 0; j < 4; ++j) {
      const int rrow = j * 64 + u;
      const float sc = (j == 2) ? C2L : -CL;
      const float4* px = (const float4*)(w_ih1 + (size_t)rrow * 64 + q * 16);
#pragma unroll
      for (int k = 0; k < 4; ++k) {
        const float4 tw = px[k];
        wx[j * 8 + 2 * k]     = pk2(tw.x, tw.y, sc);
        wx[j * 8 + 2 * k + 1] = pk2(tw.z, tw.w, sc);
      }
      const float4* ph = (const float4*)(w_hh1 + (size_t)rrow * 64 + q * 16);
#pragma unroll
      for (int k = 0; k < 4; ++k) {
        const float4 tw = ph[k];
        wh[j * 8 + 2 * k]     = pk2(tw.x, tw.y, sc);
        wh[j * 8 + 2 * k + 1] = pk2(tw.z, tw.w, sc);
      }
      const float bsc = (b_ih1[rrow] + b_hh1[rrow]) * sc;
      bi[j] = (q == 0) ? bsc : 0.0f;
    }
  }

  // per-lane activation constants: lane q activates gate q.
  // sigm lanes (q!=2): act = 0 + 1*rcp(1+exp2(a));  g lane (q==2):
  // act = C2L - C4L*rcp(1+exp2(a))  (= 2L*tanh of the pre-activation)
  const float k1 = (q == 2) ? C2L : 0.0f;
  const float k2 = (q == 2) ? -C4L : 1.0f;

  // zero h state (buffers read at t=0 / t=1 must be zero; zero all)
  if (tid < 64) {
    h0s[0][tid] = (_Float16)0.f; h0s[1][tid] = (_Float16)0.f;
    h1s[0][tid] = (_Float16)0.f; h1s[1][tid] = (_Float16)0.f;
  }

  // featB (phase 2) + h zeroing must be visible BEFORE the t=0 prefetch
  __syncthreads();

  float cc = 0.0f;   // cell state SCALED by 2*log2e; valid in lane q==0 only

  // ---- phase 4: recurrence, 513 iters, ONE barrier per iter ----
  for (int t = 0; t <= TSTEPS; ++t) {
    // prefetch layer-0 x fragment (featB immutable during loop): 8 f16 = 16B
    f16x2 xa0, xa1, xa2, xa3;
    if (layer == 0 && t < TSTEPS) {
      ldh4(featB + t * 32 + q * 8, xa0, xa1, xa2, xa3);
    }
    __syncthreads();   // h[t-1] writes visible

    const bool active = layer ? (t >= 1) : (t < TSTEPS);
    if (active) {
      float a0 = bi[0], a1 = bi[1], a2 = bi[2], a3 = bi[3];
      if (layer == 0) {
        // h-part operand read first: 16 f16 = 32 B = 2 x b128
        const _Float16* hp = h0s[(t + 1) & 1] + q * 16;
        f16x2 hv[8];
        ldh4(hp,     hv[0], hv[1], hv[2], hv[3]);
        ldh4(hp + 8, hv[4], hv[5], hv[6], hv[7]);
        // x-part: prefetched 8 of 32 input dims (4 pairs)
        FDOT2(a0, wx[0],  xa0); FDOT2(a0, wx[1],  xa1);
        FDOT2(a0, wx[2],  xa2); FDOT2(a0, wx[3],  xa3);
        FDOT2(a1, wx[4],  xa0); FDOT2(a1, wx[5],  xa1);
        FDOT2(a1, wx[6],  xa2); FDOT2(a1, wx[7],  xa3);
        FDOT2(a2, wx[8],  xa0); FDOT2(a2, wx[9],  xa1);
        FDOT2(a2, wx[10], xa2); FDOT2(a2, wx[11], xa3);
        FDOT2(a3, wx[12], xa0); FDOT2(a3, wx[13], xa1);
        FDOT2(a3, wx[14], xa2); FDOT2(a3, wx[15], xa3);
        // h-part: 16 of 64 h0[t-1] dims (8 pairs)
#pragma unroll
        for (int dd = 0; dd < 8; ++dd) {
          FDOT2(a0, wh[dd],      hv[dd]);
          FDOT2(a1, wh[8 + dd],  hv[dd]);
          FDOT2(a2, wh[16 + dd], hv[dd]);
          FDOT2(a3, wh[24 + dd], hv[dd]);
        }
      } else {
        // both operand reads first
        const _Float16* xp = h0s[(t + 1) & 1] + q * 16;
        f16x2 xv[8];
        ldh4(xp,     xv[0], xv[1], xv[2], xv[3]);
        ldh4(xp + 8, xv[4], xv[5], xv[6], xv[7]);
        const _Float16* hp = h1s[t & 1] + q * 16;
        f16x2 hv[8];
        ldh4(hp,     hv[0], hv[1], hv[2], hv[3]);
        ldh4(hp + 8, hv[4], hv[5], hv[6], hv[7]);
        // x-part: layer1 input = h0[t-1] (8 pairs)
#pragma unroll
        for (int dd = 0; dd < 8; ++dd) {
          FDOT2(a0, wx[dd],      xv[dd]);
          FDOT2(a1, wx[8 + dd],  xv[dd]);
          FDOT2(a2, wx[16 + dd], xv[dd]);
          FDOT2(a3, wx[24 + dd], xv[dd]);
        }
        // h-part: h1[t-2] (8 pairs)
#pragma unroll
        for (int dd = 0; dd < 8; ++dd) {
          FDOT2(a0, wh[dd],      hv[dd]);
          FDOT2(a1, wh[8 + dd],  hv[dd]);
          FDOT2(a2, wh[16 + dd], hv[dd]);
          FDOT2(a3, wh[24 + dd], hv[dd]);
        }
      }

      // quad butterfly all-reduce: every lane gets all 4 gate sums
      DPP_ADD(a0, 0xB1); DPP_ADD(a1, 0xB1); DPP_ADD(a2, 0xB1); DPP_ADD(a3, 0xB1);
      DPP_ADD(a0, 0x4E); DPP_ADD(a1, 0x4E); DPP_ADD(a2, 0x4E); DPP_ADD(a3, 0x4E);

      // lane-parallel activation: lane q activates gate q (uniform form)
      const float aq = (q == 0) ? a0 : (q == 1) ? a1 : (q == 2) ? a2 : a3;
      const float act = fmaf(k2, RCPF(1.0f + EXP2F(aq)), k1);
      // quad gather: valid mapping at lane q==0 (v=ii, fv=ff, gv=gs, ov=oo)
      float fv, gv, ov;
      DPP_MOV(fv, act, 0xB1);
      DPP_MOV(gv, act, 0x4E);
      DPP_MOV(ov, fv, 0x4E);
      cc = fmaf(fv, cc, act * gv);                                // 2L*c
      const float th = fmaf(-2.0f, RCPF(1.0f + EXP2F(cc)), 1.0f); // tanh(c)
      if (q == 0) {
        const float hnew = ov * th;
        if (layer == 0) h0s[t & 1][u] = (_Float16)hnew;        // h0[t]
        else            h1s[(t + 1) & 1][u] = (_Float16)hnew;  // h1[t-1]
      }
    }
  }
  __syncthreads();

  // fc epilogue: out[b, 0..4] from h1[T-1] (written at iter T into h1s[(T+1)&1])
  if (tid < 5) {
    const _Float16* h = h1s[(TSTEPS + 1) & 1];
    float s = fc_b[tid];
    const float* wrow = fc_w + tid * HID;
#pragma unroll
    for (int j = 0; j < HID; ++j) s = fmaf(wrow[j], (float)h[j], s);
    out[b * 5 + tid] = s;
  }
}

// ---------------------------------------------------------------------------
extern "C" void kernel_launch(void* const* d_in, const int* in_sizes, int n_in,
                              void* d_out, int out_size, void* d_ws, size_t ws_size,
                              hipStream_t stream) {
  (void)in_sizes; (void)n_in; (void)out_size; (void)ws_size;
  const float* x    = (const float*)d_in[0];
  const float* c1w  = (const float*)d_in[1];
  const float* c1b  = (const float*)d_in[2];
  const float* c2w  = (const float*)d_in[3];
  const float* c2b  = (const float*)d_in[4];
  const float* wih0 = (const float*)d_in[5];
  const float* whh0 = (const float*)d_in[6];
  const float* bih0 = (const float*)d_in[7];
  const float* bhh0 = (const float*)d_in[8];
  const float* wih1 = (const float*)d_in[9];
  const float* whh1 = (const float*)d_in[10];
  const float* bih1 = (const float*)d_in[11];
  const float* bhh1 = (const float*)d_in[12];
  const float* fcw  = (const float*)d_in[13];
  const float* fcb  = (const float*)d_in[14];
  float* out = (float*)d_out;

  float* t1 = (float*)d_ws;    // [256,1024,16] = 16 MB (L2-resident per block)

  fused_all<<<256, 512, 0, stream>>>(x, c1w, c1b, c2w, c2b,
                                     wih0, whh0, bih0, bhh0,
                                     wih1, whh1, bih1, bhh1,
                                     fcw, fcb, t1, out);
}

// Round 16
// 374.989 us; speedup vs baseline: 1.2265x; 1.0342x over previous
//
#include <hip/hip_runtime.h>

#define TSTEPS 512   // LSTM sequence length (2048/4)
#define HID    64

typedef _Float16 f16x2 __attribute__((ext_vector_type(2)));

// raw 2^x / 1/x (1-instr, ~1ulp; fine vs threshold)
#if __has_builtin(__builtin_amdgcn_exp2f)
#define EXP2F(x) __builtin_amdgcn_exp2f(x)
#else
#define EXP2F(x) exp2f(x)
#endif
#if __has_builtin(__builtin_amdgcn_rcpf)
#define RCPF(x) __builtin_amdgcn_rcpf(x)
#else
#define RCPF(x) (1.0f / (x))
#endif

#define CL   1.4426950408889634f   // log2(e)
#define C2L  2.8853900817779268f   // 2*log2(e)
#define C4L  5.7707801635558536f   // 4*log2(e)

// quad-lane butterfly add via DPP quad_perm (VALU-only, no LDS pipe)
#define DPP_ADD(x, ctrl)                                                       \
  x += __int_as_float(                                                         \
      __builtin_amdgcn_mov_dpp(__float_as_int(x), (ctrl), 0xf, 0xf, true))

// v_dot2_f32_f16: acc += a.x*b.x + a.y*b.y  (2 MACs/instr, f32 accumulate)
#if __has_builtin(__builtin_amdgcn_fdot2)
#define FDOT2(acc, a, b) acc = __builtin_amdgcn_fdot2((a), (b), (acc), false)
#else
#define FDOT2(acc, a, b)                                                       \
  acc = fmaf((float)(a).x, (float)(b).x,                                       \
             fmaf((float)(a).y, (float)(b).y, (acc)))
#endif

// pack two scaled f32 into one f16 pair (one-time, at weight load)
__device__ __forceinline__ f16x2 pk2(float a, float b, float sc) {
  return (f16x2){(_Float16)(a * sc), (_Float16)(b * sc)};
}

// load 16 B from LDS/global and view as 4 f16-pairs
__device__ __forceinline__ void ldh4(const void* p, f16x2& a, f16x2& b,
                                     f16x2& c, f16x2& d) {
  const uint4 t = *(const uint4*)p;
  a = __builtin_bit_cast(f16x2, t.x);
  b = __builtin_bit_cast(f16x2, t.y);
  c = __builtin_bit_cast(f16x2, t.z);
  d = __builtin_bit_cast(f16x2, t.w);
}

// ---------------------------------------------------------------------------
// ONE kernel: conv1+pool -> t1 (global, L2-resident), conv2+pool -> featB
// (LDS, f16), 2-layer pipelined LSTM recurrence + fc.
// One block per batch element: 256 blocks x 512 threads (1 block/CU).
//
// v16 = v13 CONSOLIDATION (best measured: 325.4us dispatch / 377.97 total).
// Session ladder: 642 -> 544 (quad-split+DPP, 1 barrier/iter) -> 520 (pk_fma)
// -> 498 (full fusion) -> 402 (exp2-domain tail: rcp+exp2, pre-scaled
// weights, bias-in-acc) -> 378 (f16 fdot2 core: halved reg demand + LDS).
// Falsified structural alternatives: depth-2 L1 pipeline (+1%, R12),
// LDS spin-sync instead of barrier (+27%, R14), lane-parallel activations
// (-2%, R15). Remaining floor: 513 sequential steps x ~1522cy, of which
// ~1000cy is the 8-wave barrier rendezvous required by the cross-wave h
// broadcast each step. Barrier-free needs >=192 VGPR of weights/lane
// (doesn't fit) or int8 dots (accuracy risk beyond threshold).
// ---------------------------------------------------------------------------
__global__ __launch_bounds__(512, 1) void fused_all(
    const float* __restrict__ x,
    const float* __restrict__ c1w, const float* __restrict__ c1b,
    const float* __restrict__ c2w, const float* __restrict__ c2b,
    const float* __restrict__ w_ih0, const float* __restrict__ w_hh0,
    const float* __restrict__ b_ih0, const float* __restrict__ b_hh0,
    const float* __restrict__ w_ih1, const float* __restrict__ w_hh1,
    const float* __restrict__ b_ih1, const float* __restrict__ b_hh1,
    const float* __restrict__ fc_w, const float* __restrict__ fc_b,
    float* __restrict__ t1g, float* __restrict__ out) {
  __shared__ __align__(16) _Float16 featB[512 * 32];   // 32 KB, f16
  __shared__ float ws1[144];                           // conv1 w [16][3][3]
  __shared__ float bs1[16];
  __shared__ float ws2[1536];                          // conv2 w [32][16][3]
  __shared__ float bs2[32];
  __shared__ __align__(16) _Float16 h0s[2][64];        // h0 double buffer, f16
  __shared__ __align__(16) _Float16 h1s[2][64];        // h1 double buffer, f16

  const int tid = threadIdx.x;
  const int b = blockIdx.x;

  // ---- conv weights to LDS ----
  if (tid < 144) ws1[tid] = c1w[tid];
  if (tid < 16)  bs1[tid] = c1b[tid];
  for (int i = tid; i < 1536; i += 512) ws2[i] = c2w[i];
  if (tid < 32)  bs2[tid] = c2b[tid];
  __syncthreads();

  // ---- phase 1: conv1 (3->16, k=3, same) + maxpool2, 2 positions/thread ----
  const float* xb = x + (size_t)b * 2048 * 3;
  float* t1b = t1g + (size_t)b * 1024 * 16;
#pragma unroll
  for (int rep = 0; rep < 2; ++rep) {
    const int t2 = rep * 512 + tid;       // pooled position 0..1023
    const int p0 = 2 * t2;
    float xv[4][3];
#pragma unroll
    for (int j = 0; j < 4; ++j) {
      const int p = p0 - 1 + j;
      const bool ok = (p >= 0) && (p < 2048);
#pragma unroll
      for (int c = 0; c < 3; ++c) xv[j][c] = ok ? xb[p * 3 + c] : 0.0f;
    }
    float4 o4[4];
    float* op = (float*)o4;
#pragma unroll
    for (int o = 0; o < 16; ++o) {
      float s0 = bs1[o], s1 = bs1[o];
#pragma unroll
      for (int c = 0; c < 3; ++c) {
#pragma unroll
        for (int k = 0; k < 3; ++k) {
          const float wv = ws1[(o * 3 + c) * 3 + k];
          s0 = fmaf(xv[k][c],     wv, s0);
          s1 = fmaf(xv[k + 1][c], wv, s1);
        }
      }
      op[o] = fmaxf(s0, s1);
    }
    float4* dst = (float4*)(t1b + (size_t)t2 * 16);
    dst[0] = o4[0]; dst[1] = o4[1]; dst[2] = o4[2]; dst[3] = o4[3];
  }
  __syncthreads();   // t1 writes visible block-wide

  // ---- phase 2: conv2 (16->32, k=3, same) + maxpool2 -> featB (f16) ----
  {
    const int t2 = tid;                   // pooled position 0..511
    const int p0 = 2 * t2;
    float4 r4[4][4];
    float* r = (float*)r4;                // r[j*16 + c]
#pragma unroll
    for (int j = 0; j < 4; ++j) {
      const int p = p0 - 1 + j;
      if (p >= 0 && p < 1024) {
        const float4* s = (const float4*)(t1b + p * 16);
        r4[j][0] = s[0]; r4[j][1] = s[1]; r4[j][2] = s[2]; r4[j][3] = s[3];
      } else {
        const float4 z = {0.f, 0.f, 0.f, 0.f};
        r4[j][0] = z; r4[j][1] = z; r4[j][2] = z; r4[j][3] = z;
      }
    }
    _Float16* dst = featB + (size_t)t2 * 32;
#pragma unroll 4
    for (int o = 0; o < 32; ++o) {
      float s0 = bs2[o], s1 = bs2[o];
      const float* wo = &ws2[o * 48];
#pragma unroll
      for (int c = 0; c < 16; ++c) {
        const float w0 = wo[c * 3], w1 = wo[c * 3 + 1], w2 = wo[c * 3 + 2];
        s0 = fmaf(r[0 * 16 + c], w0, s0);
        s0 = fmaf(r[1 * 16 + c], w1, s0);
        s0 = fmaf(r[2 * 16 + c], w2, s0);
        s1 = fmaf(r[1 * 16 + c], w0, s1);
        s1 = fmaf(r[2 * 16 + c], w1, s1);
        s1 = fmaf(r[3 * 16 + c], w2, s1);
      }
      dst[o] = (_Float16)fmaxf(s0, s1);
    }
  }

  // ---- phase 3: LSTM weight load -> f16 pairs, pre-scaled by log2e ----
  const int layer = tid >> 8;   // 0 or 1 (wave-uniform)
  const int lt  = tid & 255;
  const int u = lt >> 2;        // unit 0..63
  const int q = lt & 3;         // dim-quarter / quad slot

  // L0: wx[g*4+k] k<4 (8 x-dims), wh[g*8+k] k<8 (16 h-dims)
  // L1: wx[g*8+k] k<8 (16 dims),  wh[g*8+k] k<8 (16 dims)
  f16x2 wx[32], wh[32];
  float bi[4];
  if (layer == 0) {
#pragma unroll
    for (int j = 0; j < 4; ++j) {
      const int rrow = j * 64 + u;
      const float sc = (j == 2) ? C2L : CL;
      const float4* px = (const float4*)(w_ih0 + (size_t)rrow * 32 + q * 8);
      const float4 p0 = px[0], p1 = px[1];
      wx[j * 4 + 0] = pk2(p0.x, p0.y, sc);
      wx[j * 4 + 1] = pk2(p0.z, p0.w, sc);
      wx[j * 4 + 2] = pk2(p1.x, p1.y, sc);
      wx[j * 4 + 3] = pk2(p1.z, p1.w, sc);
      const float4* ph = (const float4*)(w_hh0 + (size_t)rrow * 64 + q * 16);
#pragma unroll
      for (int k = 0; k < 4; ++k) {
        const float4 tw = ph[k];
        wh[j * 8 + 2 * k]     = pk2(tw.x, tw.y, sc);
        wh[j * 8 + 2 * k + 1] = pk2(tw.z, tw.w, sc);
      }
      const float bsc = (b_ih0[rrow] + b_hh0[rrow]) * sc;
      bi[j] = (q == 0) ? bsc : 0.0f;
    }
  } else {
#pragma unroll
    for (int j = 0; j < 4; ++j) {
      const int rrow = j * 64 + u;
      const float sc = (j == 2) ? C2L : CL;
      const float4* px = (const float4*)(w_ih1 + (size_t)rrow * 64 + q * 16);
#pragma unroll
      for (int k = 0; k < 4; ++k) {
        const float4 tw = px[k];
        wx[j * 8 + 2 * k]     = pk2(tw.x, tw.y, sc);
        wx[j * 8 + 2 * k + 1] = pk2(tw.z, tw.w, sc);
      }
      const float4* ph = (const float4*)(w_hh1 + (size_t)rrow * 64 + q * 16);
#pragma unroll
      for (int k = 0; k < 4; ++k) {
        const float4 tw = ph[k];
        wh[j * 8 + 2 * k]     = pk2(tw.x, tw.y, sc);
        wh[j * 8 + 2 * k + 1] = pk2(tw.z, tw.w, sc);
      }
      const float bsc = (b_ih1[rrow] + b_hh1[rrow]) * sc;
      bi[j] = (q == 0) ? bsc : 0.0f;
    }
  }

  // zero h state (buffers read at t=0 / t=1 must be zero; zero all)
  if (tid < 64) {
    h0s[0][tid] = (_Float16)0.f; h0s[1][tid] = (_Float16)0.f;
    h1s[0][tid] = (_Float16)0.f; h1s[1][tid] = (_Float16)0.f;
  }

  // featB (phase 2) + h zeroing must be visible BEFORE the t=0 prefetch
  __syncthreads();

  float cc = 0.0f;   // cell state SCALED by 2*log2e, redundant in quad

  // ---- phase 4: recurrence, 513 iters, ONE barrier per iter ----
  for (int t = 0; t <= TSTEPS; ++t) {
    // prefetch layer-0 x fragment (featB immutable during loop): 8 f16 = 16B
    f16x2 xa0, xa1, xa2, xa3;
    if (layer == 0 && t < TSTEPS) {
      ldh4(featB + t * 32 + q * 8, xa0, xa1, xa2, xa3);
    }
    __syncthreads();   // h[t-1] writes visible

    const bool active = layer ? (t >= 1) : (t < TSTEPS);
    if (active) {
      float a0 = bi[0], a1 = bi[1], a2 = bi[2], a3 = bi[3];
      if (layer == 0) {
        // h-part operand read first: 16 f16 = 32 B = 2 x b128
        const _Float16* hp = h0s[(t + 1) & 1] + q * 16;
        f16x2 hv[8];
        ldh4(hp,     hv[0], hv[1], hv[2], hv[3]);
        ldh4(hp + 8, hv[4], hv[5], hv[6], hv[7]);
        // x-part: prefetched 8 of 32 input dims (4 pairs)
        FDOT2(a0, wx[0],  xa0); FDOT2(a0, wx[1],  xa1);
        FDOT2(a0, wx[2],  xa2); FDOT2(a0, wx[3],  xa3);
        FDOT2(a1, wx[4],  xa0); FDOT2(a1, wx[5],  xa1);
        FDOT2(a1, wx[6],  xa2); FDOT2(a1, wx[7],  xa3);
        FDOT2(a2, wx[8],  xa0); FDOT2(a2, wx[9],  xa1);
        FDOT2(a2, wx[10], xa2); FDOT2(a2, wx[11], xa3);
        FDOT2(a3, wx[12], xa0); FDOT2(a3, wx[13], xa1);
        FDOT2(a3, wx[14], xa2); FDOT2(a3, wx[15], xa3);
        // h-part: 16 of 64 h0[t-1] dims (8 pairs)
#pragma unroll
        for (int dd = 0; dd < 8; ++dd) {
          FDOT2(a0, wh[dd],      hv[dd]);
          FDOT2(a1, wh[8 + dd],  hv[dd]);
          FDOT2(a2, wh[16 + dd], hv[dd]);
          FDOT2(a3, wh[24 + dd], hv[dd]);
        }
      } else {
        // both operand reads first
        const _Float16* xp = h0s[(t + 1) & 1] + q * 16;
        f16x2 xv[8];
        ldh4(xp,     xv[0], xv[1], xv[2], xv[3]);
        ldh4(xp + 8, xv[4], xv[5], xv[6], xv[7]);
        const _Float16* hp = h1s[t & 1] + q * 16;
        f16x2 hv[8];
        ldh4(hp,     hv[0], hv[1], hv[2], hv[3]);
        ldh4(hp + 8, hv[4], hv[5], hv[6], hv[7]);
        // x-part: layer1 input = h0[t-1] (8 pairs)
#pragma unroll
        for (int dd = 0; dd < 8; ++dd) {
          FDOT2(a0, wx[dd],      xv[dd]);
          FDOT2(a1, wx[8 + dd],  xv[dd]);
          FDOT2(a2, wx[16 + dd], xv[dd]);
          FDOT2(a3, wx[24 + dd], xv[dd]);
        }
        // h-part: h1[t-2] (8 pairs)
#pragma unroll
        for (int dd = 0; dd < 8; ++dd) {
          FDOT2(a0, wh[dd],      hv[dd]);
          FDOT2(a1, wh[8 + dd],  hv[dd]);
          FDOT2(a2, wh[16 + dd], hv[dd]);
          FDOT2(a3, wh[24 + dd], hv[dd]);
        }
      }

      // quad butterfly over the 4 dim-quarters (accs already scalar f32)
      DPP_ADD(a0, 0xB1); DPP_ADD(a1, 0xB1); DPP_ADD(a2, 0xB1); DPP_ADD(a3, 0xB1);
      DPP_ADD(a0, 0x4E); DPP_ADD(a1, 0x4E); DPP_ADD(a2, 0x4E); DPP_ADD(a3, 0x4E);

      // exp2-domain update: a0,a1,a3 = log2e*p(i,f,o); a2 = 2log2e*p(g)
      const float ii = RCPF(1.0f + EXP2F(-a0));                 // sigm(pi)
      const float ff = RCPF(1.0f + EXP2F(-a1));                 // sigm(pf)
      const float gs = fmaf(-C4L, RCPF(1.0f + EXP2F(a2)), C2L); // 2L*tanh(pg)
      const float oo = RCPF(1.0f + EXP2F(-a3));                 // sigm(po)
      cc = fmaf(ff, cc, ii * gs);                               // 2L*c
      const float th = fmaf(-2.0f, RCPF(1.0f + EXP2F(cc)), 1.0f); // tanh(c)
      const float hnew = oo * th;
      if (q == 0) {
        if (layer == 0) h0s[t & 1][u] = (_Float16)hnew;        // h0[t]
        else            h1s[(t + 1) & 1][u] = (_Float16)hnew;  // h1[t-1]
      }
    }
  }
  __syncthreads();

  // fc epilogue: out[b, 0..4] from h1[T-1] (written at iter T into h1s[(T+1)&1])
  if (tid < 5) {
    const _Float16* h = h1s[(TSTEPS + 1) & 1];
    float s = fc_b[tid];
    const float* wrow = fc_w + tid * HID;
#pragma unroll
    for (int j = 0; j < HID; ++j) s = fmaf(wrow[j], (float)h[j], s);
    out[b * 5 + tid] = s;
  }
}

// ---------------------------------------------------------------------------
extern "C" void kernel_launch(void* const* d_in, const int* in_sizes, int n_in,
                              void* d_out, int out_size, void* d_ws, size_t ws_size,
                              hipStream_t stream) {
  (void)in_sizes; (void)n_in; (void)out_size; (void)ws_size;
  const float* x    = (const float*)d_in[0];
  const float* c1w  = (const float*)d_in[1];
  const float* c1b  = (const float*)d_in[2];
  const float* c2w  = (const float*)d_in[3];
  const float* c2b  = (const float*)d_in[4];
  const float* wih0 = (const float*)d_in[5];
  const float* whh0 = (const float*)d_in[6];
  const float* bih0 = (const float*)d_in[7];
  const float* bhh0 = (const float*)d_in[8];
  const float* wih1 = (const float*)d_in[9];
  const float* whh1 = (const float*)d_in[10];
  const float* bih1 = (const float*)d_in[11];
  const float* bhh1 = (const float*)d_in[12];
  const float* fcw  = (const float*)d_in[13];
  const float* fcb  = (const float*)d_in[14];
  float* out = (float*)d_out;

  float* t1 = (float*)d_ws;    // [256,1024,16] = 16 MB (L2-resident per block)

  fused_all<<<256, 512, 0, stream>>>(x, c1w, c1b, c2w, c2b,
                                     wih0, whh0, bih0, bhh0,
                                     wih1, whh1, bih1, bhh1,
                                     fcw, fcb, t1, out);
}